// Round 11
// baseline (42.829 us; speedup 1.0000x reference)
//
#include <hip/hip_runtime.h>

// Kuramoto helix network v12 = v11 + counted-sync step loop.
//  - STEP barriers: raw s_waitcnt lgkmcnt(0) + s_barrier (NO vmcnt drain,
//    unlike __syncthreads) -> global K prefetch rides across step barriers.
//  - K reg double-buffer (BfA/BfB, 32+32 VGPR): layer l+1's 16 dwordx4
//    issued at step 0 of layer l (~6000 cyc of compute hides ~2700 cyc L2).
//    Reg budget: 32+32+~42 ~= 106 <= 128 cap of launch_bounds(1024,4).
//  - Split accumulators (kf even/odd): MFMA dep chain 8 -> 4+add.
// Rest identical to v11 (full-M 16-row A, 1024-thr block/CU, grid 256,
// f16 hi/lo encoder, frag-layout prep kernel, slot-swizzled LDS dbuf).

#define NB 2048
#define NIN 512
#define NOUT 128
#define NOSC 256
#define DTT 0.1f

#define WS_WENC (512*1024)
#define WS_WD   (1024*1024)

typedef _Float16 f16;
typedef _Float16 f16x4 __attribute__((ext_vector_type(4)));
typedef _Float16 f16x8 __attribute__((ext_vector_type(8)));
typedef float f32x4 __attribute__((ext_vector_type(4)));

__device__ __forceinline__ float wrapf(float t) {
    return t - 6.28318530717958648f * rintf(t * 0.159154943091895336f);
}

// ---- prep: lay K (f16), W_enc (f16 hi/lo), W_dec (f16) out in frag layout ----
__global__ __launch_bounds__(256) void helix_prep(
    const float* __restrict__ Ks, const float* __restrict__ Wenc,
    const float* __restrict__ Wdec, char* __restrict__ ws)
{
    const int g = blockIdx.x * 256 + threadIdx.x;
    if (g < 32768) {                       // K: [l 4][nt 16][kf 8][ln 64]
        const int ln = g & 63, lg = ln >> 4, lr = ln & 15;
        const int kf = (g >> 6) & 7, nt = (g >> 9) & 15, l = (g >> 13) & 3;
        const float* s = Ks + (((size_t)l * NOSC + nt * 16 + lr) * NOSC + kf * 32 + lg * 8);
        f16x8 o;
        #pragma unroll
        for (int e = 0; e < 8; ++e) o[e] = (f16)s[e];
        *(f16x8*)(ws + (size_t)g * 16) = o;
    } else if (g < 65536) {                // Wenc: [nt 16][kf 16][h 2][ln 64]
        const int q = g - 32768;
        const int ln = q & 63, lg = ln >> 4, lr = ln & 15;
        const int h = (q >> 6) & 1, kf = (q >> 7) & 15, nt = (q >> 11) & 15;
        const float* s = Wenc + ((size_t)(nt * 16 + lr) * NIN + kf * 32 + lg * 8);
        f16x8 o;
        #pragma unroll
        for (int e = 0; e < 8; ++e) {
            float v = s[e];
            f16 hi = (f16)v;
            o[e] = h ? (f16)(v - (float)hi) : hi;
        }
        *(f16x8*)(ws + WS_WENC + (size_t)q * 16) = o;
    } else if (g < 69632) {                // Wdec: [nt 8][kf 8][ln 64]
        const int q = g - 65536;
        const int ln = q & 63, lg = ln >> 4, lr = ln & 15;
        const int kf = (q >> 6) & 7, nt = (q >> 9) & 7;
        const float* s = Wdec + ((size_t)(nt * 16 + lr) * NOSC + kf * 32 + lg * 8);
        f16x8 o;
        #pragma unroll
        for (int e = 0; e < 8; ++e) o[e] = (f16)s[e];
        *(f16x8*)(ws + WS_WD + (size_t)q * 16) = o;
    }
}

__global__ __launch_bounds__(1024, 4) void helix12(
    const float* __restrict__ x,
    const float* __restrict__ b_enc,
    const float* __restrict__ omegas,
    const float* __restrict__ Kgl,
    const float* __restrict__ mgl,
    const float* __restrict__ b_dec,
    const char* __restrict__ ws,
    float* __restrict__ out)
{
    __shared__ __align__(16) char smem[25600];
    float* th_lds = (float*)(smem + 16384);
    float* cohPS  = (float*)(smem + 24576);           // [16 wv][8 r]
    float* cohPC  = (float*)(smem + 25088);

    const int tid = threadIdx.x;           // 0..1023
    const int wv = tid >> 6, ln = tid & 63, lg = ln >> 4, lr = ln & 15;
    const int d  = lr >> 3;
    const int row0 = blockIdx.x * 8;
    const int jb  = 16 * wv + lr;          // this lane's oscillator column

    float* out_y   = out;
    float* out_th  = out + (size_t)NB * NOUT;
    float* out_coh = out + (size_t)NB * (NOUT + NOSC);

    const int4 zz = make_int4(0, 0, 0, 0);

    // ---- per-layer constants (static, in regs) ----
    float dtccA[4], omL[4];
    #pragma unroll
    for (int l = 0; l < 4; ++l) {
        dtccA[l] = DTT * Kgl[l] * (1.0f / (float)NOSC) * (mgl[l] * 0.5f);
        omL[l]   = DTT * omegas[l * NOSC + jb];
    }

    // ---- P0: x -> encoder-A LDS, rows m = 2r+h (hi/lo interleaved) ----
    {
        const int r  = tid >> 7;            // 0..7
        const int j0 = (tid & 127) << 2;    // 4 f32 per thread
        float4 v = *(const float4*)(x + (size_t)(row0 + r) * NIN + j0);
        float vv[4] = {v.x, v.y, v.z, v.w};
        f16x4 hi, lo;
        #pragma unroll
        for (int e = 0; e < 4; ++e) {
            hi[e] = (f16)vv[e];
            lo[e] = (f16)(vv[e] - (float)hi[e]);
        }
        char* base = smem + (j0 >> 5) * 1024 + ((j0 >> 3) & 3) * 256 + (j0 & 7) * 2;
        *(f16x4*)(base + (2 * r) * 16)     = hi;
        *(f16x4*)(base + (2 * r + 1) * 16) = lo;
    }
    __syncthreads();

    // ---- K double-buffer: wave wv owns col-tile wv ----
    f16x8 BfA[8], BfB[8];
    auto loadK = [&](const int l, f16x8 (&B)[8]) {
        const char* kb = ws + (size_t)l * 131072 + (size_t)wv * 8192 + ln * 16;
        #pragma unroll
        for (int kf = 0; kf < 8; ++kf)
            B[kf] = *(const f16x8*)(kb + kf * 1024);
    };

    // ---- P1: encoder MFMA (full M; hi/lo combine local) ----
    float th[2], sv[2], cv[2];
    {
        f32x4 accH = {0,0,0,0}, accL = {0,0,0,0};
        const char* aBase = smem + lg * 256 + lr * 16;
        const char* wE = ws + WS_WENC + (size_t)wv * 32768 + ln * 16;
        #pragma unroll 4
        for (int kf = 0; kf < 16; ++kf) {
            f16x8 a  = *(const f16x8*)(aBase + kf * 1024);
            f16x8 bh = *(const f16x8*)(wE + kf * 2048);
            f16x8 bl = *(const f16x8*)(wE + kf * 2048 + 1024);
            accH = __builtin_amdgcn_mfma_f32_16x16x32_f16(a, bh, accH, 0, 0, 0);
            accL = __builtin_amdgcn_mfma_f32_16x16x32_f16(a, bl, accL, 0, 0, 0);
        }
        loadK(0, BfA);   // layer-0 K streams under the epilogue + prefill
        const float be = b_enc[jb];
        #pragma unroll
        for (int p = 0; p < 2; ++p) {
            float tval = accH[2*p] + accH[2*p+1] + accL[2*p] + accL[2*p+1] + be;
            th[p] = wrapf(tval);
            __sincosf(th[p], &sv[p], &cv[p]);
        }
    }
    __syncthreads();   // encoder A-reads done before dynamics overwrites

    // ---- dynamics addresses ----
    const int rb = lg * 256 + (lr ^ ((lg & 1) << 1)) * 16;
    const int wbase = (jb >> 5) * 1024 + ((jb >> 3) & 3) * 256 + (lr & 7) * 2;
    const int wz0 = wbase + (((4 * lg + 0) ^ (d << 1)) << 4);
    const int wz1 = wbase + (((4 * lg + 1) ^ (d << 1)) << 4);
    const int wz2 = wbase + (((4 * lg + 2) ^ (d << 1)) << 4);
    const int wz3 = wbase + (((4 * lg + 3) ^ (d << 1)) << 4);

    // ---- prefill buf0 with initial S/C ----
    *(f16*)(smem + wz0) = (f16)sv[0];
    *(f16*)(smem + wz1) = (f16)cv[0];
    *(f16*)(smem + wz2) = (f16)sv[1];
    *(f16*)(smem + wz3) = (f16)cv[1];
    __syncthreads();

    // ---- dynamics step: raw-barrier (no vmcnt drain), split-acc ----
    auto STEP = [&](const char* Sb, char* Wb, const f16x8 (&Bc)[8],
                    const float om, const float cc) {
        f32x4 accE = {0.f,0.f,0.f,0.f}, accO = {0.f,0.f,0.f,0.f};
        __builtin_amdgcn_s_setprio(1);
        #pragma unroll
        for (int kf = 0; kf < 8; kf += 2) {
            f16x8 a0 = *(const f16x8*)(Sb + kf * 1024 + rb);
            f16x8 a1 = *(const f16x8*)(Sb + (kf + 1) * 1024 + rb);
            accE = __builtin_amdgcn_mfma_f32_16x16x32_f16(a0, Bc[kf],     accE, 0, 0, 0);
            accO = __builtin_amdgcn_mfma_f32_16x16x32_f16(a1, Bc[kf + 1], accO, 0, 0, 0);
        }
        f32x4 acc = accE + accO;
        #pragma unroll
        for (int p = 0; p < 2; ++p) {
            float diff = fmaf(cv[p], acc[2*p], -(sv[p] * acc[2*p+1]));
            th[p] += fmaf(diff, cc, om);
            __sincosf(th[p], &sv[p], &cv[p]);
        }
        *(f16*)(Wb + wz0) = (f16)sv[0];
        *(f16*)(Wb + wz1) = (f16)cv[0];
        *(f16*)(Wb + wz2) = (f16)sv[1];
        *(f16*)(Wb + wz3) = (f16)cv[1];
        __builtin_amdgcn_s_setprio(0);
        // my ds_reads AND ds_writes retired; globals (K prefetch) stay in flight
        asm volatile("s_waitcnt lgkmcnt(0)" ::: "memory");
        __builtin_amdgcn_s_barrier();
    };

    auto runLayer = [&](const f16x8 (&Bc)[8], f16x8 (&Bn)[8], const int lNext,
                        const float om, const float cc) {
        #pragma unroll 1
        for (int p5 = 0; p5 < 5; ++p5) {
            if (p5 == 0 && lNext >= 0) loadK(lNext, Bn);   // issue early, lands ~step 4-5
            STEP(smem,        smem + 8192, Bc, om, cc);
            STEP(smem + 8192, smem,        Bc, om, cc);
        }
    };

    runLayer(BfA, BfB, 1,  omL[0], dtccA[0]);
    runLayer(BfB, BfA, 2,  omL[1], dtccA[1]);
    runLayer(BfA, BfB, 3,  omL[2], dtccA[2]);
    runLayer(BfB, BfA, -1, omL[3], dtccA[3]);

    // ---- epilogue ----
    {
        const int dbase = (jb >> 5) * 1024 + ((jb >> 3) & 3) * 256 + (lr & 7) * 2;
        #pragma unroll
        for (int p = 0; p < 2; ++p) {
            const float wt = wrapf(th[p]);
            th_lds[(2 * lg + p) * NOSC + jb] = wt;
            *(f16*)(smem + dbase + (2 * lg + p) * 16) = (f16)wt;
        }
    }
    #pragma unroll
    for (int p = 0; p < 2; ++p) {
        float pS = sv[p], pC = cv[p];
        pS += __shfl_xor(pS, 1); pC += __shfl_xor(pC, 1);
        pS += __shfl_xor(pS, 2); pC += __shfl_xor(pC, 2);
        pS += __shfl_xor(pS, 4); pC += __shfl_xor(pC, 4);
        pS += __shfl_xor(pS, 8); pC += __shfl_xor(pC, 8);
        if (lr == 0) {
            cohPS[wv * 8 + 2 * lg + p] = pS;
            cohPC[wv * 8 + 2 * lg + p] = pC;
        }
    }
    __syncthreads();

    if (tid < 8)   // zero granule per kf for decoder rows 8-15
        *(int4*)(smem + tid * 1024 + 128) = zz;
    if (tid < 512) {   // theta out, coalesced
        float4 v = ((const float4*)th_lds)[tid];
        *(float4*)(out_th + (size_t)row0 * NOSC + tid * 4) = v;
    }
    if (tid < 8) {     // coherence
        float S = 0.f, C = 0.f;
        #pragma unroll
        for (int w2 = 0; w2 < 16; ++w2) {
            S += cohPS[w2 * 8 + tid];
            C += cohPC[w2 * 8 + tid];
        }
        S *= (1.0f / (float)NOSC);
        C *= (1.0f / (float)NOSC);
        out_coh[row0 + tid] = sqrtf(S * S + C * C);
    }
    __syncthreads();

    // decoder MFMA: waves 0-7 -> out col-tile wv; rows 8-15 broadcast-zero
    if (wv < 8) {
        const int rbD = (lr < 8) ? (lg * 256 + lr * 16) : 128;
        f32x4 aD = {0.f, 0.f, 0.f, 0.f};
        #pragma unroll
        for (int kf = 0; kf < 8; ++kf) {
            f16x8 a  = *(const f16x8*)(smem + kf * 1024 + rbD);
            f16x8 bw = *(const f16x8*)(ws + WS_WD + (size_t)wv * 8192 + kf * 1024 + ln * 16);
            aD = __builtin_amdgcn_mfma_f32_16x16x32_f16(a, bw, aD, 0, 0, 0);
        }
        if (lg < 2) {
            const int col = 16 * wv + lr;
            const float bd = b_dec[col];
            #pragma unroll
            for (int e = 0; e < 4; ++e)
                out_y[(size_t)(row0 + 4 * lg + e) * NOUT + col] = aD[e] + bd;
        }
    }
}

extern "C" void kernel_launch(void* const* d_in, const int* in_sizes, int n_in,
                              void* d_out, int out_size, void* d_ws, size_t ws_size,
                              hipStream_t stream) {
    const float* x     = (const float*)d_in[0];
    const float* W_enc = (const float*)d_in[1];
    const float* b_enc = (const float*)d_in[2];
    const float* Ks    = (const float*)d_in[3];
    const float* omg   = (const float*)d_in[4];
    const float* Kgl   = (const float*)d_in[5];
    const float* mgl   = (const float*)d_in[6];
    const float* W_dec = (const float*)d_in[7];
    const float* b_dec = (const float*)d_in[8];
    char* ws = (char*)d_ws;

    helix_prep<<<272, 256, 0, stream>>>(Ks, W_enc, W_dec, ws);
    helix12<<<NB / 8, 1024, 0, stream>>>(x, b_enc, omg, Kgl, mgl, b_dec, ws, (float*)d_out);
}